// Round 1
// baseline (60.808 us; speedup 1.0000x reference)
//
#include <hip/hip_runtime.h>

#define BB 8
#define NN 256
#define DD 128
#define LN_EPS 1e-5f

// ---------------------------------------------------------------------------
// k_proj: hi = x @ W1[:D],  hjb = x @ W1[D:] + b1
// grid = B*N/16 blocks of 256 threads; 16 rows per block; 8 rows per thread.
// ---------------------------------------------------------------------------
__global__ __launch_bounds__(256) void k_proj(const float* __restrict__ x,
                                              const float* __restrict__ w1,
                                              const float* __restrict__ b1,
                                              float* __restrict__ hi,
                                              float* __restrict__ hjb) {
    __shared__ float x_t[16][DD];
    const int row0 = blockIdx.x * 16;
    const int tid = threadIdx.x;
    for (int t = tid; t < 16 * DD; t += 256)
        x_t[t >> 7][t & 127] = x[row0 * DD + t];
    __syncthreads();

    const int dp = tid & 127;
    const int rg = tid >> 7;  // 0..1
    float acc_a[8] = {0.f, 0.f, 0.f, 0.f, 0.f, 0.f, 0.f, 0.f};
    float acc_b[8] = {0.f, 0.f, 0.f, 0.f, 0.f, 0.f, 0.f, 0.f};
    #pragma unroll 4
    for (int k = 0; k < DD; ++k) {
        float wa = w1[k * DD + dp];
        float wb = w1[(DD + k) * DD + dp];
        #pragma unroll
        for (int r = 0; r < 8; ++r) {
            float xv = x_t[rg * 8 + r][k];
            acc_a[r] = fmaf(xv, wa, acc_a[r]);
            acc_b[r] = fmaf(xv, wb, acc_b[r]);
        }
    }
    float bb = b1[dp];
    #pragma unroll
    for (int r = 0; r < 8; ++r) {
        int row = row0 + rg * 8 + r;
        hi[row * DD + dp]  = acc_a[r];
        hjb[row * DD + dp] = acc_b[r] + bb;
    }
}

// ---------------------------------------------------------------------------
// k_asum: asum[b,i] = sum_{j != i} adj[b,i,j]
// one wave per row; grid = B*N/4 blocks of 256 threads.
// ---------------------------------------------------------------------------
__global__ __launch_bounds__(256) void k_asum(const float* __restrict__ adj,
                                              float* __restrict__ asum) {
    int row = blockIdx.x * 4 + (threadIdx.x >> 6);  // [0, B*N)
    int lane = threadIdx.x & 63;
    int b = row >> 8, i = row & 255;
    const float* arow = adj + (b * NN + i) * NN;
    float s = 0.f;
    #pragma unroll
    for (int j0 = 0; j0 < NN; j0 += 64) {
        int j = j0 + lane;
        float v = arow[j];
        s += (j == i) ? 0.f : v;
    }
    #pragma unroll
    for (int m = 32; m; m >>= 1) s += __shfl_down(s, m);
    if (lane == 0) asum[row] = s;
}

// ---------------------------------------------------------------------------
// k_pair: s[b,i,d] = sum_{j != i} relu(hi[b,i,d] + hjb[b,j,d]) * adj[b,i,j]
// grid = B*(N/8) blocks of 512 threads; 8 receiver rows i per block,
// adjacency tile (masked) staged in LDS; each thread owns 2 rows at one d.
// ---------------------------------------------------------------------------
__global__ __launch_bounds__(512) void k_pair(const float* __restrict__ adj,
                                              const float* __restrict__ hi,
                                              const float* __restrict__ hjb,
                                              float* __restrict__ s_out) {
    __shared__ float a_t[8][NN];
    const int b  = blockIdx.x >> 5;
    const int i0 = (blockIdx.x & 31) * 8;
    const int tid = threadIdx.x;
    for (int t = tid; t < 8 * NN; t += 512) {
        int il = t >> 8, j = t & 255;
        int i = i0 + il;
        float av = adj[(b * NN + i) * NN + j];
        a_t[il][j] = (j == i) ? 0.f : av;
    }
    __syncthreads();

    const int dp = tid & 127;
    const int ip = tid >> 7;  // 0..3
    const int il0 = ip * 2, il1 = ip * 2 + 1;
    const float hib0 = hi[(b * NN + i0 + il0) * DD + dp];
    const float hib1 = hi[(b * NN + i0 + il1) * DD + dp];
    float acc0 = 0.f, acc1 = 0.f;
    const float* hj = hjb + b * NN * DD + dp;
    #pragma unroll 4
    for (int j = 0; j < NN; ++j) {
        float hv = hj[j * DD];
        float h0 = fmaxf(hib0 + hv, 0.f);
        float h1 = fmaxf(hib1 + hv, 0.f);
        acc0 = fmaf(h0, a_t[il0][j], acc0);
        acc1 = fmaf(h1, a_t[il1][j], acc1);
    }
    s_out[(b * NN + i0 + il0) * DD + dp] = acc0;
    s_out[(b * NN + i0 + il1) * DD + dp] = acc1;
}

// ---------------------------------------------------------------------------
// k_tail: agg = s @ w2 + b2*asum; u1 = relu(x@w3[:D] + agg@w3[D:] + b3);
//         upd = u1 @ w4 + b4; res = x + upd; out = LN(res)*g + beta
// grid = B*N/16 blocks of 256 threads; 16 rows per block, all fused via LDS.
// ---------------------------------------------------------------------------
__global__ __launch_bounds__(256) void k_tail(const float* __restrict__ x,
                                              const float* __restrict__ s_in,
                                              const float* __restrict__ asum,
                                              const float* __restrict__ w2,
                                              const float* __restrict__ b2,
                                              const float* __restrict__ w3,
                                              const float* __restrict__ b3,
                                              const float* __restrict__ w4,
                                              const float* __restrict__ b4,
                                              const float* __restrict__ g,
                                              const float* __restrict__ beta,
                                              float* __restrict__ out) {
    __shared__ float buf0[16][DD];  // s, later u1
    __shared__ float buf1[16][DD];  // agg, later res
    __shared__ float x_t[16][DD];
    __shared__ float mu_s[16], rs_s[16];
    const int row0 = blockIdx.x * 16;
    const int tid = threadIdx.x;
    for (int t = tid; t < 16 * DD; t += 256) {
        buf0[t >> 7][t & 127] = s_in[row0 * DD + t];
        x_t[t >> 7][t & 127]  = x[row0 * DD + t];
    }
    __syncthreads();

    const int dp = tid & 127;
    const int rg = tid >> 7;  // 0..1

    // Stage A: agg = s @ w2 + b2 * asum  -> buf1
    {
        float acc[8] = {0.f, 0.f, 0.f, 0.f, 0.f, 0.f, 0.f, 0.f};
        #pragma unroll 4
        for (int k = 0; k < DD; ++k) {
            float w = w2[k * DD + dp];
            #pragma unroll
            for (int r = 0; r < 8; ++r)
                acc[r] = fmaf(buf0[rg * 8 + r][k], w, acc[r]);
        }
        float bv = b2[dp];
        #pragma unroll
        for (int r = 0; r < 8; ++r) {
            int rr = rg * 8 + r;
            buf1[rr][dp] = acc[r] + bv * asum[row0 + rr];
        }
    }
    __syncthreads();

    // Stage B: u1 = relu(x @ w3[:D] + agg @ w3[D:] + b3)  -> buf0
    {
        float acc[8] = {0.f, 0.f, 0.f, 0.f, 0.f, 0.f, 0.f, 0.f};
        #pragma unroll 2
        for (int k = 0; k < DD; ++k) {
            float wa = w3[k * DD + dp];
            float wb = w3[(DD + k) * DD + dp];
            #pragma unroll
            for (int r = 0; r < 8; ++r) {
                int rr = rg * 8 + r;
                acc[r] = fmaf(x_t[rr][k], wa, acc[r]);
                acc[r] = fmaf(buf1[rr][k], wb, acc[r]);
            }
        }
        float bv = b3[dp];
        __syncthreads();  // all reads of buf1(agg)+buf0(s) complete before overwrite
        #pragma unroll
        for (int r = 0; r < 8; ++r) {
            int rr = rg * 8 + r;
            buf0[rr][dp] = fmaxf(acc[r] + bv, 0.f);
        }
    }
    __syncthreads();

    // Stage C: upd = u1 @ w4 + b4; res = x + upd  -> buf1
    {
        float acc[8] = {0.f, 0.f, 0.f, 0.f, 0.f, 0.f, 0.f, 0.f};
        #pragma unroll 4
        for (int k = 0; k < DD; ++k) {
            float w = w4[k * DD + dp];
            #pragma unroll
            for (int r = 0; r < 8; ++r)
                acc[r] = fmaf(buf0[rg * 8 + r][k], w, acc[r]);
        }
        float bv = b4[dp];
        __syncthreads();  // all reads of buf1(agg) complete before overwrite
        #pragma unroll
        for (int r = 0; r < 8; ++r) {
            int rr = rg * 8 + r;
            buf1[rr][dp] = x_t[rr][dp] + acc[r] + bv;
        }
    }
    __syncthreads();

    // Stage D: LayerNorm over d per row
    {
        int rr = tid >> 4, l16 = tid & 15;
        float s1 = 0.f, s2 = 0.f;
        #pragma unroll
        for (int m = 0; m < 8; ++m) {
            float v = buf1[rr][l16 + 16 * m];
            s1 += v;
            s2 += v * v;
        }
        #pragma unroll
        for (int m = 1; m < 16; m <<= 1) {
            s1 += __shfl_xor(s1, m);
            s2 += __shfl_xor(s2, m);
        }
        if (l16 == 0) {
            float mu = s1 * (1.f / DD);
            float var = s2 * (1.f / DD) - mu * mu;
            mu_s[rr] = mu;
            rs_s[rr] = rsqrtf(var + LN_EPS);
        }
    }
    __syncthreads();
    {
        float gv = g[dp], bv = beta[dp];
        #pragma unroll
        for (int r = 0; r < 8; ++r) {
            int rr = rg * 8 + r;
            float v = (buf1[rr][dp] - mu_s[rr]) * rs_s[rr];
            out[(row0 + rr) * DD + dp] = fmaf(v, gv, bv);
        }
    }
}

extern "C" void kernel_launch(void* const* d_in, const int* in_sizes, int n_in,
                              void* d_out, int out_size, void* d_ws, size_t ws_size,
                              hipStream_t stream) {
    (void)in_sizes; (void)n_in; (void)out_size; (void)ws_size;
    const float* x      = (const float*)d_in[0];
    const float* adj    = (const float*)d_in[1];
    const float* msg_w1 = (const float*)d_in[2];
    const float* msg_b1 = (const float*)d_in[3];
    const float* msg_w2 = (const float*)d_in[4];
    const float* msg_b2 = (const float*)d_in[5];
    const float* upd_w1 = (const float*)d_in[6];
    const float* upd_b1 = (const float*)d_in[7];
    const float* upd_w2 = (const float*)d_in[8];
    const float* upd_b2 = (const float*)d_in[9];
    const float* ln_g   = (const float*)d_in[10];
    const float* ln_b   = (const float*)d_in[11];
    float* out = (float*)d_out;

    float* ws   = (float*)d_ws;
    float* hi   = ws;                    // B*N*D
    float* hjb  = ws + BB * NN * DD;     // B*N*D
    float* s    = ws + 2 * BB * NN * DD; // B*N*D
    float* asum = ws + 3 * BB * NN * DD; // B*N

    k_proj<<<dim3(BB * NN / 16), dim3(256), 0, stream>>>(x, msg_w1, msg_b1, hi, hjb);
    k_asum<<<dim3(BB * NN / 4), dim3(256), 0, stream>>>(adj, asum);
    k_pair<<<dim3(BB * NN / 8), dim3(512), 0, stream>>>(adj, hi, hjb, s);
    k_tail<<<dim3(BB * NN / 16), dim3(256), 0, stream>>>(x, s, asum, msg_w2, msg_b2,
                                                         upd_w1, upd_b1, upd_w2, upd_b2,
                                                         ln_g, ln_b, out);
}

// Round 2
// 50.151 us; speedup vs baseline: 1.2125x; 1.2125x over previous
//
#include <hip/hip_runtime.h>

#define BB 8
#define NN 256
#define DD 128
#define LN_EPS 1e-5f

// ---------------------------------------------------------------------------
// k_proj: hi = x @ w1[:D],  hjb = x @ w1[D:] + b1
// grid 256 blocks (8 rows each) x 512 threads: dp = tid&127 (output col),
// kg = tid>>7 (k-quarter). Row operand x read via wave-uniform (scalar) loads,
// weights via coalesced VMEM. Partials combined through LDS.
// ---------------------------------------------------------------------------
__global__ __launch_bounds__(512) void k_proj(const float* __restrict__ x,
                                              const float* __restrict__ w1,
                                              const float* __restrict__ b1,
                                              float* __restrict__ hi,
                                              float* __restrict__ hjb) {
    __shared__ float part_a[4][8][DD];
    __shared__ float part_b[4][8][DD];
    const int row0 = blockIdx.x * 8;
    const int tid  = threadIdx.x;
    const int dp   = tid & 127;
    const int kg   = tid >> 7;     // 0..3
    const int kb   = kg * 32;

    const float* __restrict__ wpa = w1 + dp;            // w1[k][dp], k in [0,128)
    const float* __restrict__ wpb = w1 + DD * DD + dp;  // w1[D+k][dp]

    float acc_a[8] = {}, acc_b[8] = {};
    #pragma unroll
    for (int k4 = 0; k4 < 8; ++k4) {
        const int k0 = kb + k4 * 4;
        float wa[4], wb[4];
        #pragma unroll
        for (int q = 0; q < 4; ++q) {
            wa[q] = wpa[(k0 + q) * DD];
            wb[q] = wpb[(k0 + q) * DD];
        }
        #pragma unroll
        for (int r = 0; r < 8; ++r) {
            const float* __restrict__ xr = x + (row0 + r) * DD + k0;  // uniform -> s_load
            #pragma unroll
            for (int q = 0; q < 4; ++q) {
                acc_a[r] = fmaf(xr[q], wa[q], acc_a[r]);
                acc_b[r] = fmaf(xr[q], wb[q], acc_b[r]);
            }
        }
    }
    #pragma unroll
    for (int r = 0; r < 8; ++r) {
        part_a[kg][r][dp] = acc_a[r];
        part_b[kg][r][dp] = acc_b[r];
    }
    __syncthreads();
    #pragma unroll
    for (int m = 0; m < 2; ++m) {
        int idx = tid + m * 512;            // 0..1023
        int r = idx >> 7, d = idx & 127;
        float sa = part_a[0][r][d] + part_a[1][r][d] + part_a[2][r][d] + part_a[3][r][d];
        float sb = part_b[0][r][d] + part_b[1][r][d] + part_b[2][r][d] + part_b[3][r][d];
        hi [(row0 + r) * DD + d] = sa;
        hjb[(row0 + r) * DD + d] = sb + b1[d];
    }
}

// ---------------------------------------------------------------------------
// k_pair: s[b,i,d] += sum_{j in half, j!=i} relu(hi[b,i,d]+hjb[b,j,d])*adj[b,i,j]
// also asum[b,i] += sum of masked adjacency over the half.
// grid 256 = (b:8)x(ig:16)x(jh:2); 16 rows, 128 j per block; 256 threads:
// dq = tid&31 (4 d's), rg = tid>>5 (2 rows). hjb staged in LDS tiles of 64 j.
// Two jh blocks combine via unsafeAtomicAdd (2 commutative fp32 adds ->
// deterministic); s/asum zeroed by memset each launch.
// ---------------------------------------------------------------------------
__global__ __launch_bounds__(256) void k_pair(const float* __restrict__ adj,
                                              const float* __restrict__ hi,
                                              const float* __restrict__ hjb,
                                              float* __restrict__ s_out,
                                              float* __restrict__ asum) {
    __shared__ float a_t[16][128];   // masked adjacency slice
    __shared__ float hjs[64][DD];    // hjb tile
    const int bid = blockIdx.x;
    const int b   = bid >> 5;
    const int ig  = (bid >> 1) & 15;
    const int jh  = bid & 1;
    const int i0  = ig * 16;
    const int j0  = jh * 128;
    const int tid = threadIdx.x;

    // stage masked adjacency: 16x128 floats
    #pragma unroll
    for (int t = 0; t < 8; ++t) {
        int idx = tid + t * 256;            // 0..2047
        int il = idx >> 7, j = idx & 127;
        int i_g = i0 + il, j_g = j0 + j;
        float av = adj[(b * NN + i_g) * NN + j_g];
        a_t[il][j] = (j_g == i_g) ? 0.f : av;
    }
    __syncthreads();

    // asum partial for this j-half
    {
        int il = tid >> 4, l = tid & 15;
        float s = 0.f;
        #pragma unroll
        for (int m = 0; m < 8; ++m) s += a_t[il][l + 16 * m];
        #pragma unroll
        for (int m = 8; m; m >>= 1) s += __shfl_xor(s, m, 16);
        if (l == 0) unsafeAtomicAdd(&asum[b * NN + i0 + il], s);
    }

    const int dq = tid & 31;       // d0 = dq*4
    const int rg = tid >> 5;       // 0..7
    const int r0 = rg * 2, r1 = r0 + 1;
    const float4 hi0 = *(const float4*)&hi[(b * NN + i0 + r0) * DD + dq * 4];
    const float4 hi1 = *(const float4*)&hi[(b * NN + i0 + r1) * DD + dq * 4];
    float4 acc0 = {0.f, 0.f, 0.f, 0.f}, acc1 = {0.f, 0.f, 0.f, 0.f};

    for (int jt = 0; jt < 2; ++jt) {
        __syncthreads();   // previous-tile reads done before overwrite
        const float4* src = (const float4*)(hjb + (b * NN + j0 + jt * 64) * DD);
        #pragma unroll
        for (int t = 0; t < 8; ++t) {
            int idx = tid + t * 256;        // 0..2047 float4s = 64x128 floats
            ((float4*)hjs)[idx] = src[idx];
        }
        __syncthreads();
        #pragma unroll 4
        for (int jj = 0; jj < 64; ++jj) {
            const int j = jt * 64 + jj;
            const float4 hv = *(const float4*)&hjs[jj][dq * 4];
            const float a0 = a_t[r0][j];
            const float a1 = a_t[r1][j];
            float4 h;
            h.x = fmaxf(hi0.x + hv.x, 0.f);
            h.y = fmaxf(hi0.y + hv.y, 0.f);
            h.z = fmaxf(hi0.z + hv.z, 0.f);
            h.w = fmaxf(hi0.w + hv.w, 0.f);
            acc0.x = fmaf(h.x, a0, acc0.x);
            acc0.y = fmaf(h.y, a0, acc0.y);
            acc0.z = fmaf(h.z, a0, acc0.z);
            acc0.w = fmaf(h.w, a0, acc0.w);
            h.x = fmaxf(hi1.x + hv.x, 0.f);
            h.y = fmaxf(hi1.y + hv.y, 0.f);
            h.z = fmaxf(hi1.z + hv.z, 0.f);
            h.w = fmaxf(hi1.w + hv.w, 0.f);
            acc1.x = fmaf(h.x, a1, acc1.x);
            acc1.y = fmaf(h.y, a1, acc1.y);
            acc1.z = fmaf(h.z, a1, acc1.z);
            acc1.w = fmaf(h.w, a1, acc1.w);
        }
    }
    float* sp0 = &s_out[(b * NN + i0 + r0) * DD + dq * 4];
    float* sp1 = &s_out[(b * NN + i0 + r1) * DD + dq * 4];
    unsafeAtomicAdd(sp0 + 0, acc0.x);
    unsafeAtomicAdd(sp0 + 1, acc0.y);
    unsafeAtomicAdd(sp0 + 2, acc0.z);
    unsafeAtomicAdd(sp0 + 3, acc0.w);
    unsafeAtomicAdd(sp1 + 0, acc1.x);
    unsafeAtomicAdd(sp1 + 1, acc1.y);
    unsafeAtomicAdd(sp1 + 2, acc1.z);
    unsafeAtomicAdd(sp1 + 3, acc1.w);
}

// ---------------------------------------------------------------------------
// k_tail: agg = s@w2 + b2*asum; u1 = relu(x@w3a + agg@w3b + b3);
//         upd = u1@w4 + b4; res = x + upd; out = LN(res)*g + beta
// grid 256 blocks (8 rows) x 512 threads: dp = tid&127, kg = tid>>7.
// Row operands (s, x) via scalar loads; in-block operands (agg, u1) via
// b128 LDS broadcast; weights via VMEM; 4-way k-partials combined in LDS.
// ---------------------------------------------------------------------------
__global__ __launch_bounds__(512) void k_tail(const float* __restrict__ x,
                                              const float* __restrict__ s_in,
                                              const float* __restrict__ asum,
                                              const float* __restrict__ w2,
                                              const float* __restrict__ b2,
                                              const float* __restrict__ w3,
                                              const float* __restrict__ b3,
                                              const float* __restrict__ w4,
                                              const float* __restrict__ b4,
                                              const float* __restrict__ g,
                                              const float* __restrict__ bet,
                                              float* __restrict__ out) {
    __shared__ float part[4][8][DD];   // 16KB
    __shared__ float aggs[8][DD];      // 4KB
    __shared__ float u1s[8][DD];       // 4KB
    __shared__ float resS[8][DD];      // 4KB
    __shared__ float asum_s[8];

    const int row0 = blockIdx.x * 8;
    const int tid  = threadIdx.x;
    const int dp   = tid & 127;
    const int kg   = tid >> 7;
    const int kb   = kg * 32;

    if (tid < 8) asum_s[tid] = asum[row0 + tid];

    // ---- stage A: agg = s@w2 (+ b2*asum at combine)
    {
        float acc[8] = {};
        const float* __restrict__ wp = w2 + dp;
        #pragma unroll
        for (int k4 = 0; k4 < 8; ++k4) {
            const int k0 = kb + k4 * 4;
            float wv[4];
            #pragma unroll
            for (int q = 0; q < 4; ++q) wv[q] = wp[(k0 + q) * DD];
            #pragma unroll
            for (int r = 0; r < 8; ++r) {
                const float* __restrict__ sr = s_in + (row0 + r) * DD + k0;  // uniform
                #pragma unroll
                for (int q = 0; q < 4; ++q) acc[r] = fmaf(sr[q], wv[q], acc[r]);
            }
        }
        #pragma unroll
        for (int r = 0; r < 8; ++r) part[kg][r][dp] = acc[r];
    }
    __syncthreads();
    #pragma unroll
    for (int m = 0; m < 2; ++m) {
        int idx = tid + m * 512;
        int r = idx >> 7, d = idx & 127;
        aggs[r][d] = part[0][r][d] + part[1][r][d] + part[2][r][d] + part[3][r][d]
                   + b2[d] * asum_s[r];
    }
    __syncthreads();

    // ---- stage B: u1 = relu(x@w3a + agg@w3b + b3)
    {
        float acc[8] = {};
        const float* __restrict__ wpa = w3 + dp;            // rows 0..127 (x part)
        const float* __restrict__ wpb = w3 + DD * DD + dp;  // rows 128..255 (agg part)
        #pragma unroll
        for (int k4 = 0; k4 < 8; ++k4) {
            const int k0 = kb + k4 * 4;
            float wa[4], wb[4];
            #pragma unroll
            for (int q = 0; q < 4; ++q) {
                wa[q] = wpa[(k0 + q) * DD];
                wb[q] = wpb[(k0 + q) * DD];
            }
            #pragma unroll
            for (int r = 0; r < 8; ++r) {
                const float4 av = *(const float4*)&aggs[r][k0];   // LDS b128 broadcast
                const float* __restrict__ xr = x + (row0 + r) * DD + k0;  // uniform
                acc[r] = fmaf(xr[0], wa[0], acc[r]);
                acc[r] = fmaf(xr[1], wa[1], acc[r]);
                acc[r] = fmaf(xr[2], wa[2], acc[r]);
                acc[r] = fmaf(xr[3], wa[3], acc[r]);
                acc[r] = fmaf(av.x, wb[0], acc[r]);
                acc[r] = fmaf(av.y, wb[1], acc[r]);
                acc[r] = fmaf(av.z, wb[2], acc[r]);
                acc[r] = fmaf(av.w, wb[3], acc[r]);
            }
        }
        #pragma unroll
        for (int r = 0; r < 8; ++r) part[kg][r][dp] = acc[r];
    }
    __syncthreads();
    #pragma unroll
    for (int m = 0; m < 2; ++m) {
        int idx = tid + m * 512;
        int r = idx >> 7, d = idx & 127;
        float v = part[0][r][d] + part[1][r][d] + part[2][r][d] + part[3][r][d] + b3[d];
        u1s[r][d] = fmaxf(v, 0.f);
    }
    __syncthreads();

    // ---- stage C: upd = u1@w4; res = x + upd + b4
    {
        float acc[8] = {};
        const float* __restrict__ wp = w4 + dp;
        #pragma unroll
        for (int k4 = 0; k4 < 8; ++k4) {
            const int k0 = kb + k4 * 4;
            float wv[4];
            #pragma unroll
            for (int q = 0; q < 4; ++q) wv[q] = wp[(k0 + q) * DD];
            #pragma unroll
            for (int r = 0; r < 8; ++r) {
                const float4 uv = *(const float4*)&u1s[r][k0];    // LDS b128 broadcast
                acc[r] = fmaf(uv.x, wv[0], acc[r]);
                acc[r] = fmaf(uv.y, wv[1], acc[r]);
                acc[r] = fmaf(uv.z, wv[2], acc[r]);
                acc[r] = fmaf(uv.w, wv[3], acc[r]);
            }
        }
        #pragma unroll
        for (int r = 0; r < 8; ++r) part[kg][r][dp] = acc[r];
    }
    __syncthreads();
    #pragma unroll
    for (int m = 0; m < 2; ++m) {
        int idx = tid + m * 512;
        int r = idx >> 7, d = idx & 127;
        resS[r][d] = x[(row0 + r) * DD + d]
                   + part[0][r][d] + part[1][r][d] + part[2][r][d] + part[3][r][d]
                   + b4[d];
    }
    __syncthreads();

    // ---- LayerNorm: one row per wave (8 waves, 8 rows), 2 d's per lane
    {
        const int r = tid >> 6, l = tid & 63;
        const float2 v = *(const float2*)&resS[r][l * 2];
        float s1 = v.x + v.y;
        float s2 = v.x * v.x + v.y * v.y;
        #pragma unroll
        for (int m = 32; m; m >>= 1) {
            s1 += __shfl_xor(s1, m);
            s2 += __shfl_xor(s2, m);
        }
        const float mu = s1 * (1.f / DD);
        const float rs = rsqrtf(s2 * (1.f / DD) - mu * mu + LN_EPS);
        const int d = l * 2;
        const float2 gv = *(const float2*)&g[d];
        const float2 bv = *(const float2*)&bet[d];
        float2 o;
        o.x = (v.x - mu) * rs * gv.x + bv.x;
        o.y = (v.y - mu) * rs * gv.y + bv.y;
        *(float2*)&out[(row0 + r) * DD + d] = o;
    }
}

extern "C" void kernel_launch(void* const* d_in, const int* in_sizes, int n_in,
                              void* d_out, int out_size, void* d_ws, size_t ws_size,
                              hipStream_t stream) {
    (void)in_sizes; (void)n_in; (void)out_size; (void)ws_size;
    const float* x      = (const float*)d_in[0];
    const float* adj    = (const float*)d_in[1];
    const float* msg_w1 = (const float*)d_in[2];
    const float* msg_b1 = (const float*)d_in[3];
    const float* msg_w2 = (const float*)d_in[4];
    const float* msg_b2 = (const float*)d_in[5];
    const float* upd_w1 = (const float*)d_in[6];
    const float* upd_b1 = (const float*)d_in[7];
    const float* upd_w2 = (const float*)d_in[8];
    const float* upd_b2 = (const float*)d_in[9];
    const float* ln_g   = (const float*)d_in[10];
    const float* ln_b   = (const float*)d_in[11];
    float* out = (float*)d_out;

    float* ws   = (float*)d_ws;
    float* s    = ws;                       // B*N*D   = 262144 floats
    float* asum = ws + BB * NN * DD;        // B*N     =   2048 floats
    float* hi   = asum + BB * NN;           // B*N*D
    float* hjb  = hi + BB * NN * DD;        // B*N*D

    // zero the atomic accumulators (s + asum) every call
    hipMemsetAsync(ws, 0, (size_t)(BB * NN * DD + BB * NN) * sizeof(float), stream);

    k_proj<<<dim3(BB * NN / 8), dim3(512), 0, stream>>>(x, msg_w1, msg_b1, hi, hjb);
    k_pair<<<dim3(256), dim3(256), 0, stream>>>(adj, hi, hjb, s, asum);
    k_tail<<<dim3(BB * NN / 8), dim3(512), 0, stream>>>(x, s, asum, msg_w2, msg_b2,
                                                        upd_w1, upd_b1, upd_w2, upd_b2,
                                                        ln_g, ln_b, out);
}

// Round 3
// 43.583 us; speedup vs baseline: 1.3952x; 1.1507x over previous
//
#include <hip/hip_runtime.h>

#define BB 8
#define NN 256
#define DD 128
#define LN_EPS 1e-5f

// ---------------------------------------------------------------------------
// k_proj: hi = x @ w1[:D],  hjb = x @ w1[D:] + b1
// grid 256 blocks (8 rows each) x 512 threads: dp = tid&127 (output col),
// kg = tid>>7 (k-quarter, wave-uniform -> forced to SGPR). Row operand x via
// scalar loads, weights via coalesced VMEM. Partials combined through LDS.
// ---------------------------------------------------------------------------
__global__ __launch_bounds__(512) void k_proj(const float* __restrict__ x,
                                              const float* __restrict__ w1,
                                              const float* __restrict__ b1,
                                              float* __restrict__ hi,
                                              float* __restrict__ hjb) {
    __shared__ float part_a[4][8][DD];
    __shared__ float part_b[4][8][DD];
    const int row0 = blockIdx.x * 8;
    const int tid  = threadIdx.x;
    const int dp   = tid & 127;
    const int kb   = __builtin_amdgcn_readfirstlane((tid >> 7) * 32);  // wave-uniform
    const int kg   = kb >> 5;

    const float* __restrict__ wpa = w1 + dp;            // w1[k][dp], k in [0,128)
    const float* __restrict__ wpb = w1 + DD * DD + dp;  // w1[D+k][dp]

    float acc_a[8] = {}, acc_b[8] = {};
    #pragma unroll
    for (int k4 = 0; k4 < 8; ++k4) {
        const int k0 = kb + k4 * 4;
        float wa[4], wb[4];
        #pragma unroll
        for (int q = 0; q < 4; ++q) {
            wa[q] = wpa[(k0 + q) * DD];
            wb[q] = wpb[(k0 + q) * DD];
        }
        #pragma unroll
        for (int r = 0; r < 8; ++r) {
            const float* __restrict__ xr = x + (row0 + r) * DD + k0;  // scalar loads
            #pragma unroll
            for (int q = 0; q < 4; ++q) {
                acc_a[r] = fmaf(xr[q], wa[q], acc_a[r]);
                acc_b[r] = fmaf(xr[q], wb[q], acc_b[r]);
            }
        }
    }
    #pragma unroll
    for (int r = 0; r < 8; ++r) {
        part_a[kg][r][dp] = acc_a[r];
        part_b[kg][r][dp] = acc_b[r];
    }
    __syncthreads();
    #pragma unroll
    for (int m = 0; m < 2; ++m) {
        int idx = tid + m * 512;            // 0..1023
        int r = idx >> 7, d = idx & 127;
        float sa = part_a[0][r][d] + part_a[1][r][d] + part_a[2][r][d] + part_a[3][r][d];
        float sb = part_b[0][r][d] + part_b[1][r][d] + part_b[2][r][d] + part_b[3][r][d];
        hi [(row0 + r) * DD + d] = sa;
        hjb[(row0 + r) * DD + d] = sb + b1[d];
    }
}

// ---------------------------------------------------------------------------
// k_pair: s_h[b,i,d] = sum_{j in half, j!=i} relu(hi[b,i,d]+hjb[b,j,d])*adj[b,i,j]
// asum_h[b,i] = masked half-row sum of adjacency.
// grid 512 = (b:8)x(ig:32)x(jh:2); 8 rows x 128 j per block; 256 threads:
// dq = tid&31 (4 d's), rg = tid>>5 (row). Each j-half writes its OWN buffer
// (s0/s1, asum0/asum1) -> no atomics, no zero-init. hjb staged in LDS tiles.
// ---------------------------------------------------------------------------
__global__ __launch_bounds__(256) void k_pair(const float* __restrict__ adj,
                                              const float* __restrict__ hi,
                                              const float* __restrict__ hjb,
                                              float* __restrict__ s_base,
                                              float* __restrict__ asum_base) {
    __shared__ float a_t[8][128];    // masked adjacency slice (4KB)
    __shared__ float hjs[64][DD];    // hjb tile (32KB)
    const int bid = blockIdx.x;
    const int jh  = bid & 1;
    const int ig  = (bid >> 1) & 31;
    const int b   = bid >> 6;
    const int i0  = ig * 8;
    const int j0  = jh * 128;
    const int tid = threadIdx.x;

    float* __restrict__ s_out = s_base + (size_t)jh * BB * NN * DD;
    float* __restrict__ asum  = asum_base + jh * BB * NN;

    // stage masked adjacency: 8x128 floats
    #pragma unroll
    for (int t = 0; t < 4; ++t) {
        int idx = tid + t * 256;            // 0..1023
        int il = idx >> 7, j = idx & 127;
        int i_g = i0 + il, j_g = j0 + j;
        float av = adj[(b * NN + i_g) * NN + j_g];
        a_t[il][j] = (j_g == i_g) ? 0.f : av;
    }
    __syncthreads();

    // asum half-row sums: one row per 32-lane group
    {
        int il = tid >> 5, l = tid & 31;
        float s = 0.f;
        #pragma unroll
        for (int m = 0; m < 4; ++m) s += a_t[il][l + 32 * m];
        #pragma unroll
        for (int m = 16; m; m >>= 1) s += __shfl_xor(s, m, 32);
        if (l == 0) asum[b * NN + i0 + il] = s;
    }

    const int dq = tid & 31;       // d0 = dq*4
    const int rg = tid >> 5;       // 0..7 (row)
    const float4 hiv = *(const float4*)&hi[(b * NN + i0 + rg) * DD + dq * 4];
    float4 acc = {0.f, 0.f, 0.f, 0.f};

    #pragma unroll
    for (int jt = 0; jt < 2; ++jt) {
        __syncthreads();   // previous-tile reads done before overwrite
        const float4* src = (const float4*)(hjb + (b * NN + j0 + jt * 64) * DD);
        #pragma unroll
        for (int t = 0; t < 8; ++t) {
            int idx = tid + t * 256;        // 0..2047 float4s = 64x128 floats
            ((float4*)hjs)[idx] = src[idx];
        }
        __syncthreads();
        #pragma unroll 4
        for (int jj = 0; jj < 64; ++jj) {
            const float4 hv = *(const float4*)&hjs[jj][dq * 4];
            const float a = a_t[rg][jt * 64 + jj];
            acc.x = fmaf(fmaxf(hiv.x + hv.x, 0.f), a, acc.x);
            acc.y = fmaf(fmaxf(hiv.y + hv.y, 0.f), a, acc.y);
            acc.z = fmaf(fmaxf(hiv.z + hv.z, 0.f), a, acc.z);
            acc.w = fmaf(fmaxf(hiv.w + hv.w, 0.f), a, acc.w);
        }
    }
    *(float4*)&s_out[(b * NN + i0 + rg) * DD + dq * 4] = acc;
}

// ---------------------------------------------------------------------------
// k_tail: agg = (s0+s1)@w2 + b2*(asum0+asum1); u1 = relu(x@w3a + agg@w3b + b3);
//         upd = u1@w4 + b4; res = x + upd; out = LN(res)*g + beta
// grid 256 blocks (8 rows) x 512 threads; row operands via scalar loads,
// in-block operands via b128 LDS broadcast, weights via VMEM.
// ---------------------------------------------------------------------------
__global__ __launch_bounds__(512) void k_tail(const float* __restrict__ x,
                                              const float* __restrict__ s0,
                                              const float* __restrict__ s1,
                                              const float* __restrict__ asum0,
                                              const float* __restrict__ asum1,
                                              const float* __restrict__ w2,
                                              const float* __restrict__ b2,
                                              const float* __restrict__ w3,
                                              const float* __restrict__ b3,
                                              const float* __restrict__ w4,
                                              const float* __restrict__ b4,
                                              const float* __restrict__ g,
                                              const float* __restrict__ bet,
                                              float* __restrict__ out) {
    __shared__ float part[4][8][DD];   // 16KB
    __shared__ float aggs[8][DD];      // 4KB
    __shared__ float u1s[8][DD];       // 4KB
    __shared__ float resS[8][DD];      // 4KB
    __shared__ float asum_s[8];

    const int row0 = blockIdx.x * 8;
    const int tid  = threadIdx.x;
    const int dp   = tid & 127;
    const int kb   = __builtin_amdgcn_readfirstlane((tid >> 7) * 32);  // wave-uniform
    const int kg   = kb >> 5;

    if (tid < 8) asum_s[tid] = asum0[row0 + tid] + asum1[row0 + tid];

    // ---- stage A: agg = (s0+s1)@w2 (+ b2*asum at combine)
    {
        float acc[8] = {};
        const float* __restrict__ wp = w2 + dp;
        #pragma unroll
        for (int k4 = 0; k4 < 8; ++k4) {
            const int k0 = kb + k4 * 4;
            float wv[4];
            #pragma unroll
            for (int q = 0; q < 4; ++q) wv[q] = wp[(k0 + q) * DD];
            #pragma unroll
            for (int r = 0; r < 8; ++r) {
                const float* __restrict__ sr0 = s0 + (row0 + r) * DD + k0;  // scalar
                const float* __restrict__ sr1 = s1 + (row0 + r) * DD + k0;  // scalar
                #pragma unroll
                for (int q = 0; q < 4; ++q)
                    acc[r] = fmaf(sr0[q] + sr1[q], wv[q], acc[r]);
            }
        }
        #pragma unroll
        for (int r = 0; r < 8; ++r) part[kg][r][dp] = acc[r];
    }
    __syncthreads();
    #pragma unroll
    for (int m = 0; m < 2; ++m) {
        int idx = tid + m * 512;
        int r = idx >> 7, d = idx & 127;
        aggs[r][d] = part[0][r][d] + part[1][r][d] + part[2][r][d] + part[3][r][d]
                   + b2[d] * asum_s[r];
    }
    __syncthreads();

    // ---- stage B: u1 = relu(x@w3a + agg@w3b + b3)
    {
        float acc[8] = {};
        const float* __restrict__ wpa = w3 + dp;            // rows 0..127 (x part)
        const float* __restrict__ wpb = w3 + DD * DD + dp;  // rows 128..255 (agg part)
        #pragma unroll
        for (int k4 = 0; k4 < 8; ++k4) {
            const int k0 = kb + k4 * 4;
            float wa[4], wb[4];
            #pragma unroll
            for (int q = 0; q < 4; ++q) {
                wa[q] = wpa[(k0 + q) * DD];
                wb[q] = wpb[(k0 + q) * DD];
            }
            #pragma unroll
            for (int r = 0; r < 8; ++r) {
                const float4 av = *(const float4*)&aggs[r][k0];   // LDS b128 broadcast
                const float* __restrict__ xr = x + (row0 + r) * DD + k0;  // scalar
                acc[r] = fmaf(xr[0], wa[0], acc[r]);
                acc[r] = fmaf(xr[1], wa[1], acc[r]);
                acc[r] = fmaf(xr[2], wa[2], acc[r]);
                acc[r] = fmaf(xr[3], wa[3], acc[r]);
                acc[r] = fmaf(av.x, wb[0], acc[r]);
                acc[r] = fmaf(av.y, wb[1], acc[r]);
                acc[r] = fmaf(av.z, wb[2], acc[r]);
                acc[r] = fmaf(av.w, wb[3], acc[r]);
            }
        }
        #pragma unroll
        for (int r = 0; r < 8; ++r) part[kg][r][dp] = acc[r];
    }
    __syncthreads();
    #pragma unroll
    for (int m = 0; m < 2; ++m) {
        int idx = tid + m * 512;
        int r = idx >> 7, d = idx & 127;
        float v = part[0][r][d] + part[1][r][d] + part[2][r][d] + part[3][r][d] + b3[d];
        u1s[r][d] = fmaxf(v, 0.f);
    }
    __syncthreads();

    // ---- stage C: upd = u1@w4; res = x + upd + b4
    {
        float acc[8] = {};
        const float* __restrict__ wp = w4 + dp;
        #pragma unroll
        for (int k4 = 0; k4 < 8; ++k4) {
            const int k0 = kb + k4 * 4;
            float wv[4];
            #pragma unroll
            for (int q = 0; q < 4; ++q) wv[q] = wp[(k0 + q) * DD];
            #pragma unroll
            for (int r = 0; r < 8; ++r) {
                const float4 uv = *(const float4*)&u1s[r][k0];    // LDS b128 broadcast
                acc[r] = fmaf(uv.x, wv[0], acc[r]);
                acc[r] = fmaf(uv.y, wv[1], acc[r]);
                acc[r] = fmaf(uv.z, wv[2], acc[r]);
                acc[r] = fmaf(uv.w, wv[3], acc[r]);
            }
        }
        #pragma unroll
        for (int r = 0; r < 8; ++r) part[kg][r][dp] = acc[r];
    }
    __syncthreads();
    #pragma unroll
    for (int m = 0; m < 2; ++m) {
        int idx = tid + m * 512;
        int r = idx >> 7, d = idx & 127;
        resS[r][d] = x[(row0 + r) * DD + d]
                   + part[0][r][d] + part[1][r][d] + part[2][r][d] + part[3][r][d]
                   + b4[d];
    }
    __syncthreads();

    // ---- LayerNorm: one row per wave (8 waves, 8 rows), 2 d's per lane
    {
        const int r = tid >> 6, l = tid & 63;
        const float2 v = *(const float2*)&resS[r][l * 2];
        float s1 = v.x + v.y;
        float s2 = v.x * v.x + v.y * v.y;
        #pragma unroll
        for (int m = 32; m; m >>= 1) {
            s1 += __shfl_xor(s1, m);
            s2 += __shfl_xor(s2, m);
        }
        const float mu = s1 * (1.f / DD);
        const float rs = rsqrtf(s2 * (1.f / DD) - mu * mu + LN_EPS);
        const int d = l * 2;
        const float2 gv = *(const float2*)&g[d];
        const float2 bv = *(const float2*)&bet[d];
        float2 o;
        o.x = (v.x - mu) * rs * gv.x + bv.x;
        o.y = (v.y - mu) * rs * gv.y + bv.y;
        *(float2*)&out[(row0 + r) * DD + d] = o;
    }
}

extern "C" void kernel_launch(void* const* d_in, const int* in_sizes, int n_in,
                              void* d_out, int out_size, void* d_ws, size_t ws_size,
                              hipStream_t stream) {
    (void)in_sizes; (void)n_in; (void)out_size; (void)ws_size;
    const float* x      = (const float*)d_in[0];
    const float* adj    = (const float*)d_in[1];
    const float* msg_w1 = (const float*)d_in[2];
    const float* msg_b1 = (const float*)d_in[3];
    const float* msg_w2 = (const float*)d_in[4];
    const float* msg_b2 = (const float*)d_in[5];
    const float* upd_w1 = (const float*)d_in[6];
    const float* upd_b1 = (const float*)d_in[7];
    const float* upd_w2 = (const float*)d_in[8];
    const float* upd_b2 = (const float*)d_in[9];
    const float* ln_g   = (const float*)d_in[10];
    const float* ln_b   = (const float*)d_in[11];
    float* out = (float*)d_out;

    const size_t BND = (size_t)BB * NN * DD;
    float* ws    = (float*)d_ws;
    float* s01   = ws;                   // 2 * B*N*D  (s0 | s1)
    float* asum01= ws + 2 * BND;         // 2 * B*N    (asum0 | asum1)
    float* hi    = asum01 + 2 * BB * NN; // B*N*D
    float* hjb   = hi + BND;             // B*N*D

    k_proj<<<dim3(BB * NN / 8), dim3(512), 0, stream>>>(x, msg_w1, msg_b1, hi, hjb);
    k_pair<<<dim3(512), dim3(256), 0, stream>>>(adj, hi, hjb, s01, asum01);
    k_tail<<<dim3(BB * NN / 8), dim3(512), 0, stream>>>(x, s01, s01 + BND,
                                                        asum01, asum01 + BB * NN,
                                                        msg_w2, msg_b2,
                                                        upd_w1, upd_b1, upd_w2, upd_b2,
                                                        ln_g, ln_b, out);
}

// Round 4
// 30.158 us; speedup vs baseline: 2.0163x; 1.4452x over previous
//
#include <hip/hip_runtime.h>

#define BB 8
#define NN 256
#define DD 128
#define LN_EPS 1e-5f

// ---------------------------------------------------------------------------
// k_proj: hi = x @ w1[:D],  hjb = x @ w1[D:] + b1
// grid 256 blocks (8 rows) x 512 threads: dp = tid&127 (output col),
// kg = tid>>7 (k-quarter). Row operand x staged in LDS (broadcast ds_read),
// weights via coalesced VMEM. k-partials combined through LDS.
// ---------------------------------------------------------------------------
__global__ __launch_bounds__(512) void k_proj(const float* __restrict__ x,
                                              const float* __restrict__ w1,
                                              const float* __restrict__ b1,
                                              float* __restrict__ hi,
                                              float* __restrict__ hjb) {
    __shared__ float xs[8][DD];        // 4KB
    __shared__ float part_a[4][8][DD]; // 16KB
    __shared__ float part_b[4][8][DD]; // 16KB
    const int row0 = blockIdx.x * 8;
    const int tid  = threadIdx.x;
    #pragma unroll
    for (int t = tid; t < 8 * DD; t += 512)
        xs[t >> 7][t & 127] = x[row0 * DD + t];
    __syncthreads();

    const int dp = tid & 127;
    const int kg = tid >> 7;     // 0..3
    const int kb = kg * 32;

    float acc_a[8] = {}, acc_b[8] = {};
    #pragma unroll
    for (int k4 = 0; k4 < 8; ++k4) {
        const int k0 = kb + k4 * 4;
        float wa[4], wb[4];
        #pragma unroll
        for (int q = 0; q < 4; ++q) {
            wa[q] = w1[(k0 + q) * DD + dp];
            wb[q] = w1[(DD + k0 + q) * DD + dp];
        }
        #pragma unroll
        for (int r = 0; r < 8; ++r) {
            const float4 xv = *(const float4*)&xs[r][k0];   // LDS broadcast
            acc_a[r] = fmaf(xv.x, wa[0], acc_a[r]);
            acc_a[r] = fmaf(xv.y, wa[1], acc_a[r]);
            acc_a[r] = fmaf(xv.z, wa[2], acc_a[r]);
            acc_a[r] = fmaf(xv.w, wa[3], acc_a[r]);
            acc_b[r] = fmaf(xv.x, wb[0], acc_b[r]);
            acc_b[r] = fmaf(xv.y, wb[1], acc_b[r]);
            acc_b[r] = fmaf(xv.z, wb[2], acc_b[r]);
            acc_b[r] = fmaf(xv.w, wb[3], acc_b[r]);
        }
    }
    #pragma unroll
    for (int r = 0; r < 8; ++r) {
        part_a[kg][r][dp] = acc_a[r];
        part_b[kg][r][dp] = acc_b[r];
    }
    __syncthreads();
    #pragma unroll
    for (int m = 0; m < 2; ++m) {
        int idx = tid + m * 512;            // 0..1023
        int r = idx >> 7, d = idx & 127;
        float sa = part_a[0][r][d] + part_a[1][r][d] + part_a[2][r][d] + part_a[3][r][d];
        float sb = part_b[0][r][d] + part_b[1][r][d] + part_b[2][r][d] + part_b[3][r][d];
        hi [(row0 + r) * DD + d] = sa;
        hjb[(row0 + r) * DD + d] = sb + b1[d];
    }
}

// ---------------------------------------------------------------------------
// k_pair: s_q[b,i,d] = sum_{j in quarter, j!=i} relu(hi[b,i,d]+hjb[b,j,d])*adj[b,i,j]
// asum_q[b,i] = masked quarter-row sum of adjacency.
// grid 512 = (b:8)x(ig:16)x(jq:4); 16 rows x 64 j per block; 256 threads:
// dq = tid&31 (4 d's), rg = tid>>5 (2 rows). Each j-quarter writes its OWN
// buffer -> no atomics, no zero-init. hjb + adjacency staged in LDS.
// ---------------------------------------------------------------------------
__global__ __launch_bounds__(256) void k_pair(const float* __restrict__ adj,
                                              const float* __restrict__ hi,
                                              const float* __restrict__ hjb,
                                              float* __restrict__ s_base,
                                              float* __restrict__ asum_base) {
    __shared__ float a_t[16][64];    // masked adjacency slice (4KB)
    __shared__ float hjs[64][DD];    // hjb tile (32KB)
    const int bid = blockIdx.x;
    const int jq  = bid & 3;
    const int ig  = (bid >> 2) & 15;
    const int b   = bid >> 6;
    const int i0  = ig * 16;
    const int j0  = jq * 64;
    const int tid = threadIdx.x;

    float* __restrict__ s_out = s_base + (size_t)jq * BB * NN * DD;
    float* __restrict__ asum  = asum_base + jq * BB * NN;

    // stage masked adjacency: 16x64 floats
    #pragma unroll
    for (int t = 0; t < 4; ++t) {
        int idx = tid + t * 256;            // 0..1023
        int il = idx >> 6, jj = idx & 63;
        int i_g = i0 + il, j_g = j0 + jj;
        float av = adj[(b * NN + i_g) * NN + j_g];
        a_t[il][jj] = (j_g == i_g) ? 0.f : av;
    }
    // stage hjb tile: 64 x 128 floats as float4
    {
        const float4* src = (const float4*)(hjb + (b * NN + j0) * DD);
        #pragma unroll
        for (int t = 0; t < 8; ++t) {
            int idx = tid + t * 256;        // 0..2047
            ((float4*)hjs)[idx] = src[idx];
        }
    }
    __syncthreads();

    // asum quarter-row sums: one row per 16-lane group
    {
        int il = tid >> 4, l = tid & 15;
        float s = a_t[il][l] + a_t[il][l + 16] + a_t[il][l + 32] + a_t[il][l + 48];
        #pragma unroll
        for (int m = 8; m; m >>= 1) s += __shfl_xor(s, m, 16);
        if (l == 0) asum[b * NN + i0 + il] = s;
    }

    const int dq = tid & 31;       // d0 = dq*4
    const int rg = tid >> 5;       // 0..7
    const int r0 = rg * 2, r1 = r0 + 1;
    const float4 hi0 = *(const float4*)&hi[(b * NN + i0 + r0) * DD + dq * 4];
    const float4 hi1 = *(const float4*)&hi[(b * NN + i0 + r1) * DD + dq * 4];
    float4 acc0 = {0.f, 0.f, 0.f, 0.f}, acc1 = {0.f, 0.f, 0.f, 0.f};

    #pragma unroll 4
    for (int jj = 0; jj < 64; ++jj) {
        const float4 hv = *(const float4*)&hjs[jj][dq * 4];
        const float a0 = a_t[r0][jj];
        const float a1 = a_t[r1][jj];
        acc0.x = fmaf(fmaxf(hi0.x + hv.x, 0.f), a0, acc0.x);
        acc0.y = fmaf(fmaxf(hi0.y + hv.y, 0.f), a0, acc0.y);
        acc0.z = fmaf(fmaxf(hi0.z + hv.z, 0.f), a0, acc0.z);
        acc0.w = fmaf(fmaxf(hi0.w + hv.w, 0.f), a0, acc0.w);
        acc1.x = fmaf(fmaxf(hi1.x + hv.x, 0.f), a1, acc1.x);
        acc1.y = fmaf(fmaxf(hi1.y + hv.y, 0.f), a1, acc1.y);
        acc1.z = fmaf(fmaxf(hi1.z + hv.z, 0.f), a1, acc1.z);
        acc1.w = fmaf(fmaxf(hi1.w + hv.w, 0.f), a1, acc1.w);
    }
    *(float4*)&s_out[(b * NN + i0 + r0) * DD + dq * 4] = acc0;
    *(float4*)&s_out[(b * NN + i0 + r1) * DD + dq * 4] = acc1;
}

// ---------------------------------------------------------------------------
// k_tail: agg = (Σ s_q)@w2 + b2*(Σ asum_q); u1 = relu(x@w3a + agg@w3b + b3);
//         upd = u1@w4 + b4; res = x + upd; out = LN(res)*g + beta
// grid 256 blocks (8 rows) x 512 threads; row operands staged in LDS
// (broadcast ds_read), weights via VMEM, k-partials combined in LDS.
// ---------------------------------------------------------------------------
__global__ __launch_bounds__(512) void k_tail(const float* __restrict__ x,
                                              const float* __restrict__ s_base,
                                              const float* __restrict__ asum_base,
                                              const float* __restrict__ w2,
                                              const float* __restrict__ b2,
                                              const float* __restrict__ w3,
                                              const float* __restrict__ b3,
                                              const float* __restrict__ w4,
                                              const float* __restrict__ b4,
                                              const float* __restrict__ g,
                                              const float* __restrict__ bet,
                                              float* __restrict__ out) {
    __shared__ float part[4][8][DD];   // 16KB
    __shared__ float xs[8][DD];        // 4KB
    __shared__ float ss[8][DD];        // 4KB (sum of 4 s quarters)
    __shared__ float aggs[8][DD];      // 4KB
    __shared__ float u1s[8][DD];       // 4KB
    __shared__ float resS[8][DD];      // 4KB
    __shared__ float asum_s[8];

    const int row0 = blockIdx.x * 8;
    const int tid  = threadIdx.x;
    const int dp   = tid & 127;
    const int kg   = tid >> 7;
    const int kb   = kg * 32;
    const size_t BND = (size_t)BB * NN * DD;

    #pragma unroll
    for (int t = tid; t < 8 * DD; t += 512) {
        xs[t >> 7][t & 127] = x[row0 * DD + t];
        ss[t >> 7][t & 127] = s_base[row0 * DD + t]
                            + s_base[BND + row0 * DD + t]
                            + s_base[2 * BND + row0 * DD + t]
                            + s_base[3 * BND + row0 * DD + t];
    }
    if (tid < 8) {
        int r = row0 + tid;
        asum_s[tid] = asum_base[r] + asum_base[BB * NN + r]
                    + asum_base[2 * BB * NN + r] + asum_base[3 * BB * NN + r];
    }
    __syncthreads();

    // ---- stage A: agg = ss@w2 (+ b2*asum at combine)
    {
        float acc[8] = {};
        #pragma unroll
        for (int k4 = 0; k4 < 8; ++k4) {
            const int k0 = kb + k4 * 4;
            float wv[4];
            #pragma unroll
            for (int q = 0; q < 4; ++q) wv[q] = w2[(k0 + q) * DD + dp];
            #pragma unroll
            for (int r = 0; r < 8; ++r) {
                const float4 sv = *(const float4*)&ss[r][k0];   // LDS broadcast
                acc[r] = fmaf(sv.x, wv[0], acc[r]);
                acc[r] = fmaf(sv.y, wv[1], acc[r]);
                acc[r] = fmaf(sv.z, wv[2], acc[r]);
                acc[r] = fmaf(sv.w, wv[3], acc[r]);
            }
        }
        #pragma unroll
        for (int r = 0; r < 8; ++r) part[kg][r][dp] = acc[r];
    }
    __syncthreads();
    #pragma unroll
    for (int m = 0; m < 2; ++m) {
        int idx = tid + m * 512;
        int r = idx >> 7, d = idx & 127;
        aggs[r][d] = part[0][r][d] + part[1][r][d] + part[2][r][d] + part[3][r][d]
                   + b2[d] * asum_s[r];
    }
    __syncthreads();

    // ---- stage B: u1 = relu(x@w3a + agg@w3b + b3)
    {
        float acc[8] = {};
        #pragma unroll
        for (int k4 = 0; k4 < 8; ++k4) {
            const int k0 = kb + k4 * 4;
            float wa[4], wb[4];
            #pragma unroll
            for (int q = 0; q < 4; ++q) {
                wa[q] = w3[(k0 + q) * DD + dp];
                wb[q] = w3[(DD + k0 + q) * DD + dp];
            }
            #pragma unroll
            for (int r = 0; r < 8; ++r) {
                const float4 xv = *(const float4*)&xs[r][k0];     // LDS broadcast
                const float4 av = *(const float4*)&aggs[r][k0];   // LDS broadcast
                acc[r] = fmaf(xv.x, wa[0], acc[r]);
                acc[r] = fmaf(xv.y, wa[1], acc[r]);
                acc[r] = fmaf(xv.z, wa[2], acc[r]);
                acc[r] = fmaf(xv.w, wa[3], acc[r]);
                acc[r] = fmaf(av.x, wb[0], acc[r]);
                acc[r] = fmaf(av.y, wb[1], acc[r]);
                acc[r] = fmaf(av.z, wb[2], acc[r]);
                acc[r] = fmaf(av.w, wb[3], acc[r]);
            }
        }
        #pragma unroll
        for (int r = 0; r < 8; ++r) part[kg][r][dp] = acc[r];
    }
    __syncthreads();
    #pragma unroll
    for (int m = 0; m < 2; ++m) {
        int idx = tid + m * 512;
        int r = idx >> 7, d = idx & 127;
        float v = part[0][r][d] + part[1][r][d] + part[2][r][d] + part[3][r][d] + b3[d];
        u1s[r][d] = fmaxf(v, 0.f);
    }
    __syncthreads();

    // ---- stage C: upd = u1@w4; res = x + upd + b4
    {
        float acc[8] = {};
        #pragma unroll
        for (int k4 = 0; k4 < 8; ++k4) {
            const int k0 = kb + k4 * 4;
            float wv[4];
            #pragma unroll
            for (int q = 0; q < 4; ++q) wv[q] = w4[(k0 + q) * DD + dp];
            #pragma unroll
            for (int r = 0; r < 8; ++r) {
                const float4 uv = *(const float4*)&u1s[r][k0];    // LDS broadcast
                acc[r] = fmaf(uv.x, wv[0], acc[r]);
                acc[r] = fmaf(uv.y, wv[1], acc[r]);
                acc[r] = fmaf(uv.z, wv[2], acc[r]);
                acc[r] = fmaf(uv.w, wv[3], acc[r]);
            }
        }
        #pragma unroll
        for (int r = 0; r < 8; ++r) part[kg][r][dp] = acc[r];
    }
    __syncthreads();
    #pragma unroll
    for (int m = 0; m < 2; ++m) {
        int idx = tid + m * 512;
        int r = idx >> 7, d = idx & 127;
        resS[r][d] = xs[r][d]
                   + part[0][r][d] + part[1][r][d] + part[2][r][d] + part[3][r][d]
                   + b4[d];
    }
    __syncthreads();

    // ---- LayerNorm: one row per wave (8 waves, 8 rows), 2 d's per lane
    {
        const int r = tid >> 6, l = tid & 63;
        const float2 v = *(const float2*)&resS[r][l * 2];
        float s1 = v.x + v.y;
        float s2 = v.x * v.x + v.y * v.y;
        #pragma unroll
        for (int m = 32; m; m >>= 1) {
            s1 += __shfl_xor(s1, m);
            s2 += __shfl_xor(s2, m);
        }
        const float mu = s1 * (1.f / DD);
        const float rs = rsqrtf(s2 * (1.f / DD) - mu * mu + LN_EPS);
        const int d = l * 2;
        const float2 gv = *(const float2*)&g[d];
        const float2 bv = *(const float2*)&bet[d];
        float2 o;
        o.x = (v.x - mu) * rs * gv.x + bv.x;
        o.y = (v.y - mu) * rs * gv.y + bv.y;
        *(float2*)&out[(row0 + r) * DD + d] = o;
    }
}

extern "C" void kernel_launch(void* const* d_in, const int* in_sizes, int n_in,
                              void* d_out, int out_size, void* d_ws, size_t ws_size,
                              hipStream_t stream) {
    (void)in_sizes; (void)n_in; (void)out_size; (void)ws_size;
    const float* x      = (const float*)d_in[0];
    const float* adj    = (const float*)d_in[1];
    const float* msg_w1 = (const float*)d_in[2];
    const float* msg_b1 = (const float*)d_in[3];
    const float* msg_w2 = (const float*)d_in[4];
    const float* msg_b2 = (const float*)d_in[5];
    const float* upd_w1 = (const float*)d_in[6];
    const float* upd_b1 = (const float*)d_in[7];
    const float* upd_w2 = (const float*)d_in[8];
    const float* upd_b2 = (const float*)d_in[9];
    const float* ln_g   = (const float*)d_in[10];
    const float* ln_b   = (const float*)d_in[11];
    float* out = (float*)d_out;

    const size_t BND = (size_t)BB * NN * DD;
    float* ws     = (float*)d_ws;
    float* s4     = ws;                    // 4 * B*N*D (one per j-quarter)
    float* asum4  = ws + 4 * BND;          // 4 * B*N
    float* hi     = asum4 + 4 * BB * NN;   // B*N*D
    float* hjb    = hi + BND;              // B*N*D

    k_proj<<<dim3(BB * NN / 8), dim3(512), 0, stream>>>(x, msg_w1, msg_b1, hi, hjb);
    k_pair<<<dim3(512), dim3(256), 0, stream>>>(adj, hi, hjb, s4, asum4);
    k_tail<<<dim3(BB * NN / 8), dim3(512), 0, stream>>>(x, s4, asum4,
                                                        msg_w2, msg_b2,
                                                        upd_w1, upd_b1, upd_w2, upd_b2,
                                                        ln_g, ln_b, out);
}

// Round 5
// 28.769 us; speedup vs baseline: 2.1137x; 1.0483x over previous
//
#include <hip/hip_runtime.h>

#define BB 8
#define NN 256
#define DD 128
#define LN_EPS 1e-5f

// ---------------------------------------------------------------------------
// k_proj: hi = x @ w1[:D],  hjb = x @ w1[D:] + b1
// grid 256 blocks (8 rows) x 512 threads: dp = tid&127, kg = tid>>7.
// x staged in LDS (broadcast ds_read), weights via coalesced VMEM.
// ---------------------------------------------------------------------------
__global__ __launch_bounds__(512) void k_proj(const float* __restrict__ x,
                                              const float* __restrict__ w1,
                                              const float* __restrict__ b1,
                                              float* __restrict__ hi,
                                              float* __restrict__ hjb) {
    __shared__ float xs[8][DD];        // 4KB
    __shared__ float part_a[4][8][DD]; // 16KB
    __shared__ float part_b[4][8][DD]; // 16KB
    const int row0 = blockIdx.x * 8;
    const int tid  = threadIdx.x;
    #pragma unroll
    for (int t = tid; t < 8 * DD; t += 512)
        xs[t >> 7][t & 127] = x[row0 * DD + t];
    __syncthreads();

    const int dp = tid & 127;
    const int kg = tid >> 7;     // 0..3
    const int kb = kg * 32;

    float acc_a[8] = {}, acc_b[8] = {};
    #pragma unroll
    for (int k4 = 0; k4 < 8; ++k4) {
        const int k0 = kb + k4 * 4;
        float wa[4], wb[4];
        #pragma unroll
        for (int q = 0; q < 4; ++q) {
            wa[q] = w1[(k0 + q) * DD + dp];
            wb[q] = w1[(DD + k0 + q) * DD + dp];
        }
        #pragma unroll
        for (int r = 0; r < 8; ++r) {
            const float4 xv = *(const float4*)&xs[r][k0];   // LDS broadcast
            acc_a[r] = fmaf(xv.x, wa[0], acc_a[r]);
            acc_a[r] = fmaf(xv.y, wa[1], acc_a[r]);
            acc_a[r] = fmaf(xv.z, wa[2], acc_a[r]);
            acc_a[r] = fmaf(xv.w, wa[3], acc_a[r]);
            acc_b[r] = fmaf(xv.x, wb[0], acc_b[r]);
            acc_b[r] = fmaf(xv.y, wb[1], acc_b[r]);
            acc_b[r] = fmaf(xv.z, wb[2], acc_b[r]);
            acc_b[r] = fmaf(xv.w, wb[3], acc_b[r]);
        }
    }
    #pragma unroll
    for (int r = 0; r < 8; ++r) {
        part_a[kg][r][dp] = acc_a[r];
        part_b[kg][r][dp] = acc_b[r];
    }
    __syncthreads();
    #pragma unroll
    for (int m = 0; m < 2; ++m) {
        int idx = tid + m * 512;            // 0..1023
        int r = idx >> 7, d = idx & 127;
        float sa = part_a[0][r][d] + part_a[1][r][d] + part_a[2][r][d] + part_a[3][r][d];
        float sb = part_b[0][r][d] + part_b[1][r][d] + part_b[2][r][d] + part_b[3][r][d];
        hi [(row0 + r) * DD + d] = sa;
        hjb[(row0 + r) * DD + d] = sb + b1[d];
    }
}

// ---------------------------------------------------------------------------
// k_fused: per block (8 rows): pair accumulation (s, asum stay in LDS) then
// the whole tail (agg, MLP, residual, LayerNorm). 256 blocks x 512 threads.
//
// LDS plan (floats):
//   [    0,  8192) hjs[64][128]   -> later part[8][8][128]
//   [ 8192, 10240) a_t[8][256]    -> later u1s[8][128] | resS[8][128]
//   [10240, 11264) xs[8][128]
//   [11264, 13312) sspart[16][128]; lower half -> ss, upper half -> aggs
//   [13312, 13320) asum_s[8]
// ---------------------------------------------------------------------------
__global__ __launch_bounds__(512) void k_fused(const float* __restrict__ adj,
                                               const float* __restrict__ x,
                                               const float* __restrict__ hi,
                                               const float* __restrict__ hjb,
                                               const float* __restrict__ w2,
                                               const float* __restrict__ b2,
                                               const float* __restrict__ w3,
                                               const float* __restrict__ b3,
                                               const float* __restrict__ w4,
                                               const float* __restrict__ b4,
                                               const float* __restrict__ g,
                                               const float* __restrict__ bet,
                                               float* __restrict__ out) {
    __shared__ float smem[13320];
    float* const a_t    = smem + 8192;    // [8][256]
    float* const xs     = smem + 10240;   // [8][128]
    float* const ssp    = smem + 11264;   // [16][128]
    float* const aggs   = smem + 12288;   // [8][128] (upper half of ssp)
    float* const u1s    = smem + 8192;    // [8][128] (aliases dead a_t)
    float* const resS   = smem + 9216;    // [8][128] (aliases dead a_t)
    float* const part   = smem;           // [8][8][128] (aliases dead hjs)
    float* const asum_s = smem + 13312;   // [8]

    const int bid = blockIdx.x;
    const int b   = bid >> 5;
    const int i0  = (bid & 31) * 8;
    const int tid = threadIdx.x;

    // ---- stage masked adjacency rows + x rows
    #pragma unroll
    for (int t = 0; t < 4; ++t) {
        int idx = tid + t * 512;            // 0..2047
        int il = idx >> 8, j = idx & 255;
        int i_g = i0 + il;
        float av = adj[((size_t)b * NN + i_g) * NN + j];
        a_t[il * 256 + j] = (j == i_g) ? 0.f : av;
    }
    #pragma unroll
    for (int t = 0; t < 2; ++t) {
        int idx = tid + t * 512;            // 0..1023
        xs[idx] = x[((size_t)b * NN + i0) * DD + idx];
    }
    __syncthreads();

    // ---- asum: one wave per row
    {
        int w = tid >> 6, l = tid & 63;
        float s = a_t[w * 256 + l] + a_t[w * 256 + l + 64]
                + a_t[w * 256 + l + 128] + a_t[w * 256 + l + 192];
        #pragma unroll
        for (int m = 32; m; m >>= 1) s += __shfl_xor(s, m);
        if (l == 0) asum_s[w] = s;
    }
    // asum_s consumed far later (after several syncs)

    // ---- pair phase: s[row][d] = sum_j relu(hi+hjb)*a
    const int dq  = tid & 31;       // d-quad
    const int rg  = tid >> 5;       // 0..15
    const int row = rg & 7;
    const int jh  = rg >> 3;
    const float4 hi4 = *(const float4*)&hi[((size_t)b * NN + i0 + row) * DD + dq * 4];
    float4 acc = {0.f, 0.f, 0.f, 0.f};

    for (int jt = 0; jt < 4; ++jt) {
        __syncthreads();   // prev tile reads done
        const float4* src = (const float4*)(hjb + ((size_t)b * NN + jt * 64) * DD);
        float4* dst = (float4*)smem;
        #pragma unroll
        for (int t = 0; t < 4; ++t) dst[tid + t * 512] = src[tid + t * 512];
        __syncthreads();
        const int jb = jh * 32;
        #pragma unroll 8
        for (int jj = 0; jj < 32; ++jj) {
            const int jl = jb + jj;
            const float4 hv = *(const float4*)&smem[jl * 128 + dq * 4];
            const float a = a_t[row * 256 + jt * 64 + jl];
            acc.x = fmaf(fmaxf(hi4.x + hv.x, 0.f), a, acc.x);
            acc.y = fmaf(fmaxf(hi4.y + hv.y, 0.f), a, acc.y);
            acc.z = fmaf(fmaxf(hi4.z + hv.z, 0.f), a, acc.z);
            acc.w = fmaf(fmaxf(hi4.w + hv.w, 0.f), a, acc.w);
        }
    }
    __syncthreads();       // last hjs reads done before ssp writes? (disjoint, but order part alias)
    *(float4*)&ssp[rg * 128 + dq * 4] = acc;
    __syncthreads();
    // combine j-halves into lower half (each (r,d) touched by exactly one thread)
    #pragma unroll
    for (int t = 0; t < 2; ++t) {
        int idx = tid + t * 512;
        int r = idx >> 7, d = idx & 127;
        ssp[r * 128 + d] += ssp[(r + 8) * 128 + d];
    }
    __syncthreads();

    // ---- tail mapping: 2 output cols/thread, 8-way k-split
    const int dp = tid & 63;            // cols dp, dp+64
    const int kg = tid >> 6;            // 0..7 (wave-uniform)
    const int kb = kg * 16;

    // ---- stage A: agg = ss @ w2 (+ b2*asum at combine)
    {
        float wv0[16], wv1[16];
        #pragma unroll
        for (int k = 0; k < 16; ++k) {
            wv0[k] = w2[(kb + k) * DD + dp];
            wv1[k] = w2[(kb + k) * DD + dp + 64];
        }
        #pragma unroll
        for (int r = 0; r < 8; ++r) {
            float a0 = 0.f, a1 = 0.f;
            #pragma unroll
            for (int q = 0; q < 4; ++q) {
                const float4 sv = *(const float4*)&ssp[r * 128 + kb + q * 4];
                a0 = fmaf(sv.x, wv0[q*4+0], a0); a1 = fmaf(sv.x, wv1[q*4+0], a1);
                a0 = fmaf(sv.y, wv0[q*4+1], a0); a1 = fmaf(sv.y, wv1[q*4+1], a1);
                a0 = fmaf(sv.z, wv0[q*4+2], a0); a1 = fmaf(sv.z, wv1[q*4+2], a1);
                a0 = fmaf(sv.w, wv0[q*4+3], a0); a1 = fmaf(sv.w, wv1[q*4+3], a1);
            }
            part[kg * 1024 + r * 128 + dp]      = a0;
            part[kg * 1024 + r * 128 + dp + 64] = a1;
        }
    }
    __syncthreads();
    #pragma unroll
    for (int t = 0; t < 2; ++t) {
        int idx = tid + t * 512;
        int r = idx >> 7, d = idx & 127;
        float s = part[r * 128 + d];
        #pragma unroll
        for (int w = 1; w < 8; ++w) s += part[w * 1024 + r * 128 + d];
        aggs[r * 128 + d] = s + b2[d] * asum_s[r];
    }
    __syncthreads();

    // ---- stage B: u1 = relu(x@w3a + agg@w3b + b3)
    {
        float wa0[16], wa1[16], wb0[16], wb1[16];
        #pragma unroll
        for (int k = 0; k < 16; ++k) {
            wa0[k] = w3[(kb + k) * DD + dp];
            wa1[k] = w3[(kb + k) * DD + dp + 64];
            wb0[k] = w3[(DD + kb + k) * DD + dp];
            wb1[k] = w3[(DD + kb + k) * DD + dp + 64];
        }
        #pragma unroll
        for (int r = 0; r < 8; ++r) {
            float a0 = 0.f, a1 = 0.f;
            #pragma unroll
            for (int q = 0; q < 4; ++q) {
                const float4 xv = *(const float4*)&xs[r * 128 + kb + q * 4];
                const float4 av = *(const float4*)&aggs[r * 128 + kb + q * 4];
                a0 = fmaf(xv.x, wa0[q*4+0], a0); a1 = fmaf(xv.x, wa1[q*4+0], a1);
                a0 = fmaf(xv.y, wa0[q*4+1], a0); a1 = fmaf(xv.y, wa1[q*4+1], a1);
                a0 = fmaf(xv.z, wa0[q*4+2], a0); a1 = fmaf(xv.z, wa1[q*4+2], a1);
                a0 = fmaf(xv.w, wa0[q*4+3], a0); a1 = fmaf(xv.w, wa1[q*4+3], a1);
                a0 = fmaf(av.x, wb0[q*4+0], a0); a1 = fmaf(av.x, wb1[q*4+0], a1);
                a0 = fmaf(av.y, wb0[q*4+1], a0); a1 = fmaf(av.y, wb1[q*4+1], a1);
                a0 = fmaf(av.z, wb0[q*4+2], a0); a1 = fmaf(av.z, wb1[q*4+2], a1);
                a0 = fmaf(av.w, wb0[q*4+3], a0); a1 = fmaf(av.w, wb1[q*4+3], a1);
            }
            part[kg * 1024 + r * 128 + dp]      = a0;
            part[kg * 1024 + r * 128 + dp + 64] = a1;
        }
    }
    __syncthreads();
    #pragma unroll
    for (int t = 0; t < 2; ++t) {
        int idx = tid + t * 512;
        int r = idx >> 7, d = idx & 127;
        float s = part[r * 128 + d];
        #pragma unroll
        for (int w = 1; w < 8; ++w) s += part[w * 1024 + r * 128 + d];
        u1s[r * 128 + d] = fmaxf(s + b3[d], 0.f);
    }
    __syncthreads();

    // ---- stage C: upd = u1 @ w4
    {
        float wv0[16], wv1[16];
        #pragma unroll
        for (int k = 0; k < 16; ++k) {
            wv0[k] = w4[(kb + k) * DD + dp];
            wv1[k] = w4[(kb + k) * DD + dp + 64];
        }
        #pragma unroll
        for (int r = 0; r < 8; ++r) {
            float a0 = 0.f, a1 = 0.f;
            #pragma unroll
            for (int q = 0; q < 4; ++q) {
                const float4 uv = *(const float4*)&u1s[r * 128 + kb + q * 4];
                a0 = fmaf(uv.x, wv0[q*4+0], a0); a1 = fmaf(uv.x, wv1[q*4+0], a1);
                a0 = fmaf(uv.y, wv0[q*4+1], a0); a1 = fmaf(uv.y, wv1[q*4+1], a1);
                a0 = fmaf(uv.z, wv0[q*4+2], a0); a1 = fmaf(uv.z, wv1[q*4+2], a1);
                a0 = fmaf(uv.w, wv0[q*4+3], a0); a1 = fmaf(uv.w, wv1[q*4+3], a1);
            }
            part[kg * 1024 + r * 128 + dp]      = a0;
            part[kg * 1024 + r * 128 + dp + 64] = a1;
        }
    }
    __syncthreads();
    #pragma unroll
    for (int t = 0; t < 2; ++t) {
        int idx = tid + t * 512;
        int r = idx >> 7, d = idx & 127;
        float s = part[r * 128 + d];
        #pragma unroll
        for (int w = 1; w < 8; ++w) s += part[w * 1024 + r * 128 + d];
        resS[r * 128 + d] = xs[r * 128 + d] + s + b4[d];
    }
    __syncthreads();

    // ---- LayerNorm: one wave per row, 2 d's per lane
    {
        const int r = tid >> 6, l = tid & 63;
        const float2 v = *(const float2*)&resS[r * 128 + l * 2];
        float s1 = v.x + v.y;
        float s2 = v.x * v.x + v.y * v.y;
        #pragma unroll
        for (int m = 32; m; m >>= 1) {
            s1 += __shfl_xor(s1, m);
            s2 += __shfl_xor(s2, m);
        }
        const float mu = s1 * (1.f / DD);
        const float rs = rsqrtf(s2 * (1.f / DD) - mu * mu + LN_EPS);
        const int d = l * 2;
        const float2 gv = *(const float2*)&g[d];
        const float2 bv = *(const float2*)&bet[d];
        float2 o;
        o.x = (v.x - mu) * rs * gv.x + bv.x;
        o.y = (v.y - mu) * rs * gv.y + bv.y;
        *(float2*)&out[((size_t)b * NN + i0 + r) * DD + d] = o;
    }
}

extern "C" void kernel_launch(void* const* d_in, const int* in_sizes, int n_in,
                              void* d_out, int out_size, void* d_ws, size_t ws_size,
                              hipStream_t stream) {
    (void)in_sizes; (void)n_in; (void)out_size; (void)ws_size;
    const float* x      = (const float*)d_in[0];
    const float* adj    = (const float*)d_in[1];
    const float* msg_w1 = (const float*)d_in[2];
    const float* msg_b1 = (const float*)d_in[3];
    const float* msg_w2 = (const float*)d_in[4];
    const float* msg_b2 = (const float*)d_in[5];
    const float* upd_w1 = (const float*)d_in[6];
    const float* upd_b1 = (const float*)d_in[7];
    const float* upd_w2 = (const float*)d_in[8];
    const float* upd_b2 = (const float*)d_in[9];
    const float* ln_g   = (const float*)d_in[10];
    const float* ln_b   = (const float*)d_in[11];
    float* out = (float*)d_out;

    const size_t BND = (size_t)BB * NN * DD;
    float* ws  = (float*)d_ws;
    float* hi  = ws;            // B*N*D
    float* hjb = ws + BND;      // B*N*D

    k_proj<<<dim3(BB * NN / 8), dim3(512), 0, stream>>>(x, msg_w1, msg_b1, hi, hjb);
    k_fused<<<dim3(256), dim3(512), 0, stream>>>(adj, x, hi, hjb,
                                                 msg_w2, msg_b2,
                                                 upd_w1, upd_b1, upd_w2, upd_b2,
                                                 ln_g, ln_b, out);
}